// Round 17
// baseline (218.414 us; speedup 1.0000x reference)
//
#include <hip/hip_runtime.h>
#include <cmath>

#define NN    4096
#define FIN   32
#define KSEL  39      // neighbors kept (top-40 minus self)
#define PP    22
#define PPAD  24
#define FOUT  48
#define WPB   2       // waves per block
#define QW    4       // queries per wave
#define CAP   128     // candidate cap per query (fallback if exceeded)

#define WSYNC() asm volatile("s_waitcnt lgkmcnt(0)" ::: "memory")

// order-preserving float->uint (total order, handles negatives)
__device__ __forceinline__ unsigned keyof(float f) {
    unsigned u = __float_as_uint(f);
    return ((int)u < 0) ? ~u : (u | 0x80000000u);
}
__device__ __forceinline__ float keyinv(unsigned k) {
    return ((int)k < 0) ? __uint_as_float(k & 0x7FFFFFFFu) : __uint_as_float(~k);
}

// ---------------- precompute: one thread per point -------------------------------
__global__ __launch_bounds__(256) void gn_pre(
    const float* __restrict__ x,
    const float* __restrict__ Wf, const float* __restrict__ bf,
    const float* __restrict__ Ws, const float* __restrict__ bs,
    float* __restrict__ coords4, float* __restrict__ harr, float* __restrict__ feats)
{
    int p = blockIdx.x * 256 + threadIdx.x;

    const float4* xr4 = (const float4*)(x + (size_t)p * FIN);
    float xv[FIN];
    #pragma unroll
    for (int i = 0; i < 8; ++i) {
        float4 t = xr4[i];
        xv[4*i] = t.x; xv[4*i+1] = t.y; xv[4*i+2] = t.z; xv[4*i+3] = t.w;
    }

    float fa[PP];
    #pragma unroll
    for (int c = 0; c < PP; ++c) fa[c] = bf[c];
    #pragma unroll
    for (int i = 0; i < FIN; ++i) {
        float xi = xv[i];
        #pragma unroll
        for (int c = 0; c < PP; ++c) fa[c] = fmaf(xi, Wf[i * PP + c], fa[c]);
    }

    float ca[4];
    #pragma unroll
    for (int c = 0; c < 4; ++c) ca[c] = bs[c];
    #pragma unroll
    for (int i = 0; i < FIN; ++i) {
        float xi = xv[i];
        #pragma unroll
        for (int c = 0; c < 4; ++c) ca[c] = fmaf(xi, Ws[i * 4 + c], ca[c]);
    }

    float4* fw = (float4*)(feats + (size_t)p * PPAD);
    fw[0] = make_float4(fa[0],  fa[1],  fa[2],  fa[3]);
    fw[1] = make_float4(fa[4],  fa[5],  fa[6],  fa[7]);
    fw[2] = make_float4(fa[8],  fa[9],  fa[10], fa[11]);
    fw[3] = make_float4(fa[12], fa[13], fa[14], fa[15]);
    fw[4] = make_float4(fa[16], fa[17], fa[18], fa[19]);
    fw[5] = make_float4(fa[20], fa[21], 0.f, 0.f);

    ((float4*)coords4)[p] = make_float4(ca[0], ca[1], ca[2], ca[3]);
    harr[p] = 0.5f * fmaf(ca[0], ca[0], fmaf(ca[1], ca[1], fmaf(ca[2], ca[2], ca[3] * ca[3])));
}

// ---- fallback-only helpers (degenerate C > CAP path) ----------------------------
__device__ __forceinline__ void sort64_pair(float& v, int& m, int lane) {
    #pragma unroll
    for (int k = 2; k <= 64; k <<= 1) {
        #pragma unroll
        for (int j = k >> 1; j >= 1; j >>= 1) {
            float ov = __shfl_xor(v, j);
            int   om = __shfl_xor(m, j);
            bool keepMin = (((lane & j) == 0) == ((lane & k) == 0));
            bool less = (ov < v) || (ov == v && om < m);
            bool take = (less == keepMin);
            v = take ? ov : v;
            m = take ? om : m;
        }
    }
}
__device__ __forceinline__ void merge64(float& Lv, int& Lm, float cv, int cm, int lane) {
    float rv = __shfl_xor(cv, 63);
    int   rm = __shfl_xor(cm, 63);
    bool less = (rv < Lv) || (rv == Lv && rm < Lm);
    if (less) { Lv = rv; Lm = rm; }
    #pragma unroll
    for (int j = 32; j >= 1; j >>= 1) {
        float ov = __shfl_xor(Lv, j);
        int   om = __shfl_xor(Lm, j);
        bool lower = ((lane & j) == 0);
        bool l2 = (ov < Lv) || (ov == Lv && om < Lm);
        bool take = (l2 == lower);
        Lv = take ? ov : Lv;
        Lm = take ? om : Lm;
    }
}

// ---------------- fallback per-query tail (rare; R12-identical) ------------------
__device__ __forceinline__ void tail_query_fb(
    int lane, int b, int nj, int qj,
    const float4* __restrict__ c4, const float* __restrict__ feats,
    const float* __restrict__ x, const float* __restrict__ Wo,
    const float* __restrict__ bo,
    float* __restrict__ fstage, float* __restrict__ agg,
    float* __restrict__ out)
{
    const float INF = __builtin_inff();
    const float NEGINF = -INF;
    float4 cqj = c4[nj];
    float sqnj = fmaf(cqj.x, cqj.x, fmaf(cqj.y, cqj.y, fmaf(cqj.z, cqj.z, cqj.w * cqj.w)));

    // exact streaming top-64 over all 4096
    float Lv = INF; int Lm = 0x7FFFFFFF;
    for (int c = 0; c < 64; ++c) {
        int m = c * 64 + lane;
        float4 cm = c4[m];
        float s2 = fmaf(cm.x, cm.x, fmaf(cm.y, cm.y, fmaf(cm.z, cm.z, cm.w * cm.w)));
        float dt = fmaf(cqj.x, cm.x, fmaf(cqj.y, cm.y, fmaf(cqj.z, cm.z, cqj.w * cm.w)));
        float v  = fmaxf(fmaf(-2.f, dt, s2 + sqnj), 0.f);
        if (m == nj) v = INF;
        sort64_pair(v, m, lane);
        if (c == 0) { Lv = v; Lm = m; }
        else        merge64(Lv, Lm, v, m, lane);
    }
    if (lane < KSEL) {
        float wgt = __expf(-10.f * Lv);
        const float4* fr = (const float4*)(feats + ((size_t)b * NN + Lm) * PPAD);
        float4 f0 = fr[0], f1 = fr[1], f2 = fr[2], f3 = fr[3], f4 = fr[4], f5 = fr[5];
        float4* row = (float4*)(fstage + lane * PPAD);
        row[0] = make_float4(f0.x * wgt, f0.y * wgt, f0.z * wgt, f0.w * wgt);
        row[1] = make_float4(f1.x * wgt, f1.y * wgt, f1.z * wgt, f1.w * wgt);
        row[2] = make_float4(f2.x * wgt, f2.y * wgt, f2.z * wgt, f2.w * wgt);
        row[3] = make_float4(f3.x * wgt, f3.y * wgt, f3.z * wgt, f3.w * wgt);
        row[4] = make_float4(f4.x * wgt, f4.y * wgt, f4.z * wgt, f4.w * wgt);
        row[5] = make_float4(f5.x * wgt, f5.y * wgt, f5.z * wgt, f5.w * wgt);
    }
    WSYNC();
    if (lane < 2 * PP) {
        int g  = (lane >= PP) ? 1 : 0;
        int c  = lane - g * PP;
        int k0 = g ? 20 : 0;
        int k1 = g ? KSEL : 20;
        float mx = NEGINF, sm = 0.f;
        for (int k = k0; k < k1; ++k) {
            float v = fstage[k * PPAD + c];
            mx = fmaxf(mx, v);
            sm += v;
        }
        float mx2 = __shfl(mx, lane + PP);
        float sm2 = __shfl(sm, lane + PP);
        if (lane < PP) {
            agg[c]      = fmaxf(mx, mx2);
            agg[PP + c] = (sm + sm2) * (1.f / (float)KSEL);
        }
    }
    WSYNC();
    if (lane < FOUT) {
        const float* xr = x + (size_t)qj * FIN;
        float acc = bo[lane];
        #pragma unroll
        for (int f = 0; f < FIN; ++f)
            acc = fmaf(xr[f], Wo[f * FOUT + lane], acc);
        #pragma unroll
        for (int f = 0; f < 2 * PP; ++f)
            acc = fmaf(agg[f], Wo[(FIN + f) * FOUT + lane], acc);
        float e = __expf(2.f * acc);
        float r = __builtin_amdgcn_rcpf(e + 1.f);
        out[(size_t)qj * FOUT + lane] = fmaf(-2.f, r, 1.f);
    }
    WSYNC();
}

// ---------------- stage one selected neighbor row --------------------------------
#define STAGEROW(IDX, DV)                                                            \
    {                                                                                \
        unsigned slot = atomicAdd(&cnt2_s[wv], 1u);                                  \
        float wgt = __expf(-10.f * (DV));                                            \
        const float4* fr = (const float4*)(feats + ((size_t)b * NN + (IDX)) * PPAD); \
        float4 g0 = fr[0], g1 = fr[1], g2 = fr[2], g3 = fr[3], g4 = fr[4], g5 = fr[5]; \
        float4* row = (float4*)(fstage + slot * PPAD);                               \
        row[0] = make_float4(g0.x * wgt, g0.y * wgt, g0.z * wgt, g0.w * wgt);        \
        row[1] = make_float4(g1.x * wgt, g1.y * wgt, g1.z * wgt, g1.w * wgt);        \
        row[2] = make_float4(g2.x * wgt, g2.y * wgt, g2.z * wgt, g2.w * wgt);        \
        row[3] = make_float4(g3.x * wgt, g3.y * wgt, g3.z * wgt, g3.w * wgt);        \
        row[4] = make_float4(g4.x * wgt, g4.y * wgt, g4.z * wgt, g4.w * wgt);        \
        row[5] = make_float4(g5.x * wgt, g5.y * wgt, g5.z * wgt, g5.w * wgt);        \
    }

// tie-resolve + stage + aggregate for query J (post-radix; kA/iA/dA etc live)
#define TIE_STAGE_AGG(J)                                                             \
    {                                                                                \
        int cless  = (int)__popcll(__ballot(kA##J < D##J))                           \
                   + (int)__popcll(__ballot(kB##J < D##J));                          \
        int tiecnt = (int)__popcll(__ballot(kA##J == D##J))                          \
                   + (int)__popcll(__ballot(kB##J == D##J));                         \
        int tneed = KSEL - cless;                                                    \
        unsigned TI = 0xFFFFFFFFu;                                                   \
        if (tiecnt > tneed) {                                                        \
            unsigned pi = 0;                                                         \
            for (int bit = 11; bit >= 0; --bit) {                                    \
                unsigned t = pi | (1u << bit);                                       \
                int c = (int)__popcll(__ballot((kA##J == D##J) && (iA##J < t)))      \
                      + (int)__popcll(__ballot((kB##J == D##J) && (iB##J < t)));     \
                if (c < tneed) pi = t;                                               \
            }                                                                        \
            TI = pi;                                                                 \
        }                                                                            \
        if (lane == 0) cnt2_s[wv] = 0;                                               \
        WSYNC();                                                                     \
        bool tkA = (kA##J < D##J) || ((kA##J == D##J) && (iA##J <= TI));             \
        if (tkA) STAGEROW(iA##J, dA##J);                                             \
        bool tkB = (kB##J < D##J) || ((kB##J == D##J) && (iB##J <= TI));             \
        if (tkB) STAGEROW(iB##J, dB##J);                                             \
        WSYNC();                                                                     \
        if (lane < 2 * PP) {                                                         \
            int g  = (lane >= PP) ? 1 : 0;                                           \
            int c  = lane - g * PP;                                                  \
            int k0 = g ? 20 : 0;                                                     \
            int k1 = g ? KSEL : 20;                                                  \
            float mx = NEGINF, sm = 0.f;                                             \
            for (int k = k0; k < k1; ++k) {                                          \
                float v = fstage[k * PPAD + c];                                      \
                mx = fmaxf(mx, v); sm += v;                                          \
            }                                                                        \
            float mx2 = __shfl(mx, lane + PP);                                       \
            float sm2 = __shfl(sm, lane + PP);                                       \
            if (lane < PP) {                                                         \
                aggw[(J) * 48 + c]      = fmaxf(mx, mx2);                            \
                aggw[(J) * 48 + PP + c] = (sm + sm2) * (1.f / (float)KSEL);          \
            }                                                                        \
        }                                                                            \
        WSYNC();                                                                     \
    }

// load 2 candidate chunks for query J (gathers issued together across queries)
#define LOADCAND(J, CJ, SQJ)                                                         \
    unsigned kA##J = 0xFFFFFFFFu, iA##J = 0xFFFFFFFFu; float dA##J = 0.f;            \
    if (lane < (CJ)) {                                                               \
        iA##J = (unsigned)selp[(J) * CAP + lane];                                    \
        float4 cm = c4[iA##J];                                                       \
        float s2 = fmaf(cm.x, cm.x, fmaf(cm.y, cm.y, fmaf(cm.z, cm.z, cm.w * cm.w)));\
        float dt = fmaf(cq##J.x, cm.x, fmaf(cq##J.y, cm.y, fmaf(cq##J.z, cm.z, cq##J.w * cm.w))); \
        dA##J = fmaxf(fmaf(-2.f, dt, s2 + (SQJ)), 0.f);                              \
        kA##J = __float_as_uint(dA##J);                                              \
    }                                                                                \
    unsigned kB##J = 0xFFFFFFFFu, iB##J = 0xFFFFFFFFu; float dB##J = 0.f;            \
    if (64 + lane < (CJ)) {                                                          \
        iB##J = (unsigned)selp[(J) * CAP + 64 + lane];                               \
        float4 cm = c4[iB##J];                                                       \
        float s2 = fmaf(cm.x, cm.x, fmaf(cm.y, cm.y, fmaf(cm.z, cm.z, cm.w * cm.w)));\
        float dt = fmaf(cq##J.x, cm.x, fmaf(cq##J.y, cm.y, fmaf(cq##J.z, cm.z, cq##J.w * cm.w))); \
        dB##J = fmaxf(fmaf(-2.f, dt, s2 + (SQJ)), 0.f);                              \
        kB##J = __float_as_uint(dB##J);                                              \
    }

// ---------------- main: one wave per FOUR queries --------------------------------
__global__ __launch_bounds__(WPB * 64, 8) void gn_main(
    const float* __restrict__ x,
    const float* __restrict__ Wo, const float* __restrict__ bo,
    const float* __restrict__ coords4, const float* __restrict__ harr,
    const float* __restrict__ feats,
    float* __restrict__ out)
{
    __shared__ unsigned short sel_s[WPB * QW * CAP];     // candidate indices
    __shared__ float fstage_s[WPB * KSEL * PPAD];
    __shared__ float agg_s[WPB * QW * 48];               // 4 agg buffers per wave
    __shared__ unsigned cnt_s[WPB * QW];
    __shared__ unsigned cnt2_s[WPB];

    const float INF = __builtin_inff();
    const float NEGINF = -INF;
    const int wv    = threadIdx.x >> 6;
    const int lane  = threadIdx.x & 63;
    const int qbase = (blockIdx.x * WPB + wv) * QW;      // 4 queries, same batch
    const int b     = qbase >> 12;
    const int n0    = qbase & (NN - 1);
    unsigned short* selp = sel_s + wv * QW * CAP;
    float* fstage = fstage_s + wv * (KSEL * PPAD);
    float* aggw   = agg_s + wv * (QW * 48);

    const float4* c4 = ((const float4*)coords4) + (size_t)b * NN;
    const float*  hB = harr + (size_t)b * NN;

    // per-query constants -- individual scalars only
    float4 cq0 = c4[n0 + 0], cq1 = c4[n0 + 1], cq2 = c4[n0 + 2], cq3 = c4[n0 + 3];

    if (lane < QW) cnt_s[wv * QW + lane] = 0;

    // ---- pass 1: f = h - q.m per query, running min (self included) ----
    float km0 = INF, km1 = INF, km2 = INF, km3 = INF;
    #pragma unroll 4
    for (int i = 0; i < 64; ++i) {
        int m = i * 64 + lane;
        float4 cm = c4[m];
        float hm = hB[m];
        float f0 = fmaf(-cq0.x, cm.x, hm);
        f0 = fmaf(-cq0.y, cm.y, f0);
        f0 = fmaf(-cq0.z, cm.z, f0);
        f0 = fmaf(-cq0.w, cm.w, f0);
        float f1 = fmaf(-cq1.x, cm.x, hm);
        f1 = fmaf(-cq1.y, cm.y, f1);
        f1 = fmaf(-cq1.z, cm.z, f1);
        f1 = fmaf(-cq1.w, cm.w, f1);
        float f2 = fmaf(-cq2.x, cm.x, hm);
        f2 = fmaf(-cq2.y, cm.y, f2);
        f2 = fmaf(-cq2.z, cm.z, f2);
        f2 = fmaf(-cq2.w, cm.w, f2);
        float f3 = fmaf(-cq3.x, cm.x, hm);
        f3 = fmaf(-cq3.y, cm.y, f3);
        f3 = fmaf(-cq3.z, cm.z, f3);
        f3 = fmaf(-cq3.w, cm.w, f3);
        km0 = fminf(km0, f0);
        km1 = fminf(km1, f1);
        km2 = fminf(km2, f2);
        km3 = fminf(km3, f3);
    }
    unsigned kb0 = keyof(km0);
    unsigned kb1 = keyof(km1);
    unsigned kb2 = keyof(km2);
    unsigned kb3 = keyof(km3);

    // ---- bounds: 40th-smallest lane-min f-key, TRUNCATED radix (bits 31..15),
    //      widen low bits -> exact superset threshold in f-space.
    unsigned ub0 = 0, ub1 = 0, ub2 = 0, ub3 = 0;
    for (int bit = 31; bit >= 15; --bit) {
        unsigned msk = 1u << bit;
        unsigned t0 = ub0 | msk, t1 = ub1 | msk, t2 = ub2 | msk, t3 = ub3 | msk;
        if ((int)__popcll(__ballot(kb0 < t0)) < KSEL + 1) ub0 = t0;
        if ((int)__popcll(__ballot(kb1 < t1)) < KSEL + 1) ub1 = t1;
        if ((int)__popcll(__ballot(kb2 < t2)) < KSEL + 1) ub2 = t2;
        if ((int)__popcll(__ballot(kb3 < t3)) < KSEL + 1) ub3 = t3;
    }
    // NaN-region guard: cap widened key below keyof(+inf)
    float UB0 = keyinv(min(ub0 | 0x7FFFu, 0xFF7FFFFFu));
    float UB1 = keyinv(min(ub1 | 0x7FFFu, 0xFF7FFFFFu));
    float UB2 = keyinv(min(ub2 | 0x7FFFu, 0xFF7FFFFFu));
    float UB3 = keyinv(min(ub3 | 0x7FFFu, 0xFF7FFFFFu));
    WSYNC();   // cnt init visible

    // ---- compact pass: f <= UB, store idx to LDS ----
    #pragma unroll 4
    for (int i = 0; i < 64; ++i) {
        int m = i * 64 + lane;
        float4 cm = c4[m];
        float hm = hB[m];
        float f0 = fmaf(-cq0.x, cm.x, hm);
        f0 = fmaf(-cq0.y, cm.y, f0);
        f0 = fmaf(-cq0.z, cm.z, f0);
        f0 = fmaf(-cq0.w, cm.w, f0);
        float f1 = fmaf(-cq1.x, cm.x, hm);
        f1 = fmaf(-cq1.y, cm.y, f1);
        f1 = fmaf(-cq1.z, cm.z, f1);
        f1 = fmaf(-cq1.w, cm.w, f1);
        float f2 = fmaf(-cq2.x, cm.x, hm);
        f2 = fmaf(-cq2.y, cm.y, f2);
        f2 = fmaf(-cq2.z, cm.z, f2);
        f2 = fmaf(-cq2.w, cm.w, f2);
        float f3 = fmaf(-cq3.x, cm.x, hm);
        f3 = fmaf(-cq3.y, cm.y, f3);
        f3 = fmaf(-cq3.z, cm.z, f3);
        f3 = fmaf(-cq3.w, cm.w, f3);
        if ((f0 <= UB0) && (m != n0 + 0)) {
            unsigned s = atomicAdd(&cnt_s[wv * QW + 0], 1u);
            if (s < CAP) selp[0 * CAP + s] = (unsigned short)m;
        }
        if ((f1 <= UB1) && (m != n0 + 1)) {
            unsigned s = atomicAdd(&cnt_s[wv * QW + 1], 1u);
            if (s < CAP) selp[1 * CAP + s] = (unsigned short)m;
        }
        if ((f2 <= UB2) && (m != n0 + 2)) {
            unsigned s = atomicAdd(&cnt_s[wv * QW + 2], 1u);
            if (s < CAP) selp[2 * CAP + s] = (unsigned short)m;
        }
        if ((f3 <= UB3) && (m != n0 + 3)) {
            unsigned s = atomicAdd(&cnt_s[wv * QW + 3], 1u);
            if (s < CAP) selp[3 * CAP + s] = (unsigned short)m;
        }
    }
    WSYNC();

    int C0 = (int)cnt_s[wv * QW + 0];
    int C1 = (int)cnt_s[wv * QW + 1];
    int C2 = (int)cnt_s[wv * QW + 2];
    int C3 = (int)cnt_s[wv * QW + 3];

    if (C0 <= CAP && C1 <= CAP && C2 <= CAP && C3 <= CAP) {
        // ---- batched candidate loads: 8 gathers in flight ----
        float sq0 = fmaf(cq0.x, cq0.x, fmaf(cq0.y, cq0.y, fmaf(cq0.z, cq0.z, cq0.w * cq0.w)));
        float sq1 = fmaf(cq1.x, cq1.x, fmaf(cq1.y, cq1.y, fmaf(cq1.z, cq1.z, cq1.w * cq1.w)));
        float sq2 = fmaf(cq2.x, cq2.x, fmaf(cq2.y, cq2.y, fmaf(cq2.z, cq2.z, cq2.w * cq2.w)));
        float sq3 = fmaf(cq3.x, cq3.x, fmaf(cq3.y, cq3.y, fmaf(cq3.z, cq3.z, cq3.w * cq3.w)));
        LOADCAND(0, C0, sq0)
        LOADCAND(1, C1, sq1)
        LOADCAND(2, C2, sq2)
        LOADCAND(3, C3, sq3)

        // ---- interleaved exact D-radix: 4 independent chains (ILP) ----
        unsigned D0 = 0, D1 = 0, D2 = 0, D3 = 0;
        for (int bit = 30; bit >= 0; --bit) {
            unsigned msk = 1u << bit;
            { unsigned t = D0 | msk;
              int c = (int)__popcll(__ballot(kA0 < t)) + (int)__popcll(__ballot(kB0 < t));
              if (c < KSEL) D0 = t; }
            { unsigned t = D1 | msk;
              int c = (int)__popcll(__ballot(kA1 < t)) + (int)__popcll(__ballot(kB1 < t));
              if (c < KSEL) D1 = t; }
            { unsigned t = D2 | msk;
              int c = (int)__popcll(__ballot(kA2 < t)) + (int)__popcll(__ballot(kB2 < t));
              if (c < KSEL) D2 = t; }
            { unsigned t = D3 | msk;
              int c = (int)__popcll(__ballot(kA3 < t)) + (int)__popcll(__ballot(kB3 < t));
              if (c < KSEL) D3 = t; }
        }

        // ---- per-query: ties + stage + aggregate (fstage reused serially) ----
        TIE_STAGE_AGG(0)
        TIE_STAGE_AGG(1)
        TIE_STAGE_AGG(2)
        TIE_STAGE_AGG(3)

        // ---- batched epilogue: one Wo load feeds 4 queries ----
        if (lane < FOUT) {
            const float* xr0 = x + (size_t)(qbase + 0) * FIN;
            const float* xr1 = x + (size_t)(qbase + 1) * FIN;
            const float* xr2 = x + (size_t)(qbase + 2) * FIN;
            const float* xr3 = x + (size_t)(qbase + 3) * FIN;
            float bv = bo[lane];
            float a0 = bv, a1 = bv, a2 = bv, a3 = bv;
            #pragma unroll
            for (int f = 0; f < FIN; ++f) {
                float w = Wo[f * FOUT + lane];
                a0 = fmaf(xr0[f], w, a0);
                a1 = fmaf(xr1[f], w, a1);
                a2 = fmaf(xr2[f], w, a2);
                a3 = fmaf(xr3[f], w, a3);
            }
            #pragma unroll
            for (int f = 0; f < 2 * PP; ++f) {
                float w = Wo[(FIN + f) * FOUT + lane];
                a0 = fmaf(aggw[0 * 48 + f], w, a0);
                a1 = fmaf(aggw[1 * 48 + f], w, a1);
                a2 = fmaf(aggw[2 * 48 + f], w, a2);
                a3 = fmaf(aggw[3 * 48 + f], w, a3);
            }
            float e0 = __expf(2.f * a0), e1 = __expf(2.f * a1);
            float e2 = __expf(2.f * a2), e3 = __expf(2.f * a3);
            out[(size_t)(qbase + 0) * FOUT + lane] = fmaf(-2.f, __builtin_amdgcn_rcpf(e0 + 1.f), 1.f);
            out[(size_t)(qbase + 1) * FOUT + lane] = fmaf(-2.f, __builtin_amdgcn_rcpf(e1 + 1.f), 1.f);
            out[(size_t)(qbase + 2) * FOUT + lane] = fmaf(-2.f, __builtin_amdgcn_rcpf(e2 + 1.f), 1.f);
            out[(size_t)(qbase + 3) * FOUT + lane] = fmaf(-2.f, __builtin_amdgcn_rcpf(e3 + 1.f), 1.f);
        }
    } else {
        // degenerate fallback (essentially never taken)
        tail_query_fb(lane, b, n0 + 0, qbase + 0, c4, feats, x, Wo, bo, fstage, aggw + 0 * 48, out);
        tail_query_fb(lane, b, n0 + 1, qbase + 1, c4, feats, x, Wo, bo, fstage, aggw + 1 * 48, out);
        tail_query_fb(lane, b, n0 + 2, qbase + 2, c4, feats, x, Wo, bo, fstage, aggw + 2 * 48, out);
        tail_query_fb(lane, b, n0 + 3, qbase + 3, c4, feats, x, Wo, bo, fstage, aggw + 3 * 48, out);
    }
}

extern "C" void kernel_launch(void* const* d_in, const int* in_sizes, int n_in,
                              void* d_out, int out_size, void* d_ws, size_t ws_size,
                              hipStream_t stream) {
    const float* x  = (const float*)d_in[0];
    const float* Wf = (const float*)d_in[1];
    const float* bf = (const float*)d_in[2];
    const float* Ws = (const float*)d_in[3];
    const float* bs = (const float*)d_in[4];
    const float* Wo = (const float*)d_in[5];
    const float* bo = (const float*)d_in[6];
    float* outp = (float*)d_out;

    float* ws      = (float*)d_ws;
    float* coords4 = ws;                      // 32768*4  = 131072 floats
    float* harr    = ws + 131072;             // 32768 floats
    float* feats   = ws + 131072 + 32768;     // 32768*24 = 786432 floats

    gn_pre<<<32768 / 256, 256, 0, stream>>>(x, Wf, bf, Ws, bs, coords4, harr, feats);
    gn_main<<<32768 / (WPB * QW), WPB * 64, 0, stream>>>(x, Wo, bo, coords4, harr, feats, outp);
}